// Round 2
// 181.124 us; speedup vs baseline: 1.0222x; 1.0222x over previous
//
#include <hip/hip_runtime.h>

#define IMG 1024

typedef float v4f __attribute__((ext_vector_type(4)));

// entropy of a window sum s with n = 1/inv_n elements: -(p0*log2 p0 + p1*log2 p1)
__device__ __forceinline__ float ent(float s, float inv_n) {
    float p1 = s * inv_n;
    float p0 = 1.0f - p1;
    float l1 = (p1 > 0.0f) ? __log2f(p1) : 0.0f;
    float l0 = (p0 > 0.0f) ? __log2f(p0) : 0.0f;
    return -(p0 * l0 + p1 * l1);
}

__device__ __forceinline__ float bfly_sum(float v) {
#pragma unroll
    for (int m = 32; m >= 1; m >>= 1) v += __shfl_xor(v, m);
    return v;  // full 64-lane sum, broadcast to all lanes
}

// Kernel 1: one 128x128 tile per block; levels k=2..128.
// Dense-load lane layout:
//   lane = c0*16 + c4;  c0 = row-within-4-row-group (0..3), c4 = col/4 (0..15).
//   Load i reads row (base + 4*i + c0), cols 4*c4..4*c4+3  ->  each instruction
//   covers four fully-contiguous 256B row segments (every 64B sector complete),
//   vs the old half-sector-per-instruction pattern. Loads are nontemporal
//   (each byte is read exactly once; no reuse to cache).
// Window sums are rebuilt via row merges (xor 16/32) and col merges (xor 1/2/4/8).
// Each k-window's entropy is computed redundantly on 2..64 lanes; the wave
// reduction divides the multiplicity back out.
__global__ __launch_bounds__(256, 4) void slice_k1(const float* __restrict__ x,
                                                   float* __restrict__ ws) {
    const int b    = blockIdx.x >> 6;    // image
    const int tile = blockIdx.x & 63;    // 8x8 tiles of 128x128
    const int tr = tile >> 3, tc = tile & 7;
    const int t = threadIdx.x;
    const int w = t >> 6, lane = t & 63;
    const int wr = w >> 1, wc = w & 1;   // 2x2 waves of 64x64
    const int c0 = lane >> 4;            // row offset within 4-row group (lane bits 4,5)
    const int c4 = lane & 15;            // column quad index (lane bits 0..3)

    const int row0 = tr * 128 + wr * 64 + c0;
    const int col0 = tc * 128 + wc * 64 + c4 * 4;
    const float* p = x + (size_t)b * (IMG * IMG) + (size_t)row0 * IMG + col0;

    // 16 independent fully-coalesced nontemporal loads, all issued before use.
    // Load i covers rows {4i + c0}, i.e. the wave covers rows 0..63 of its region.
    v4f v[16];
#pragma unroll
    for (int i = 0; i < 16; ++i)
        v[i] = __builtin_nontemporal_load((const v4f*)(p + (size_t)(4 * i) * IMG));

    // ---- k=2 and k=4, per 4-row group i ----
    // row pair (2r,2r+1) lives on lane pair xor 16 (c0: 0<->1, 2<->3)
    // 4-row group = xor 16 then xor 32 (c0: all four)
    float e2 = 0.f, e4 = 0.f;
    float s4[16];
#pragma unroll
    for (int i = 0; i < 16; ++i) {
        float sx = v[i].x + v[i].y;              // k2 col-window 2*c4,   this row
        float sz = v[i].z + v[i].w;              // k2 col-window 2*c4+1, this row
        float w2x = sx + __shfl_xor(sx, 16);     // 2x2 window sum (x2 multiplicity)
        float w2z = sz + __shfl_xor(sz, 16);
        e2 += ent(w2x, 0.25f) + ent(w2z, 0.25f);
        float cs = sx + sz;                      // 4 cols of this row
        float r4 = cs + __shfl_xor(cs, 16);
        float w4 = r4 + __shfl_xor(r4, 32);      // 4x4 window sum (x4 multiplicity)
        e4 += ent(w4, 1.f / 16.f);
        s4[i] = w4;
    }

    // ---- k=8: rows via i-pairs (in-register), cols via lane xor 1 ----
    float e8 = 0.f;
    float s8[8];
#pragma unroll
    for (int j = 0; j < 8; ++j) {
        float u = s4[2 * j] + s4[2 * j + 1];     // 8 rows x 4 cols
        float s = u + __shfl_xor(u, 1);          // 8x8 (x8 multiplicity)
        e8 += ent(s, 1.f / 64.f);
        s8[j] = s;
    }

    // ---- k=16: i-quads + lane xor 2 ----
    float e16 = 0.f;
    float s16[4];
#pragma unroll
    for (int q = 0; q < 4; ++q) {
        float u = s8[2 * q] + s8[2 * q + 1];     // 16 rows x 8 cols
        float s = u + __shfl_xor(u, 2);          // 16x16 (x16 multiplicity)
        e16 += ent(s, 1.f / 256.f);
        s16[q] = s;
    }

    // ---- k=32: i-halves + lane xor 4 ----
    float e32 = 0.f;
    float s32[2];
#pragma unroll
    for (int h = 0; h < 2; ++h) {
        float u = s16[2 * h] + s16[2 * h + 1];   // 32 rows x 16 cols
        float s = u + __shfl_xor(u, 4);          // 32x32 (x32 multiplicity)
        e32 += ent(s, 1.f / 1024.f);
        s32[h] = s;
    }

    // ---- k=64: all rows + lane xor 8 -> uniform across wave ----
    float u64 = s32[0] + s32[1];                 // 64 rows x 32 cols
    float s64 = u64 + __shfl_xor(u64, 8);        // 64x64, uniform on all lanes
    float e64 = ent(s64, 1.f / 4096.f);

    // wave-level sums; divide out the per-lane multiplicity
    float E2  = bfly_sum(e2)  * 0.5f;        // 1024 distinct windows, computed 2x each
    float E4  = bfly_sum(e4)  * 0.25f;       // 256, 4x
    float E8  = bfly_sum(e8)  * 0.125f;      // 64, 8x
    float E16 = bfly_sum(e16) * (1.f / 16.f);// 16, 16x
    float E32 = bfly_sum(e32) * (1.f / 32.f);// 4, 32x

    __shared__ float wl[4][8];
    if (lane == 0) {
        wl[w][0] = E2;  wl[w][1] = E4;  wl[w][2] = E8;
        wl[w][3] = E16; wl[w][4] = E32; wl[w][5] = e64; wl[w][6] = s64;
    }
    __syncthreads();
    if (t < 8) {
        float r;
        if (t < 6) {
            r = wl[0][t] + wl[1][t] + wl[2][t] + wl[3][t];
        } else {
            float s128 = wl[0][6] + wl[1][6] + wl[2][6] + wl[3][6];
            r = (t == 6) ? ent(s128, 1.f / 16384.f) : s128;
        }
        ws[(size_t)blockIdx.x * 8 + t] = r;  // {E2,E4,E8,E16,E32,E64,e128,s128}
    }
}

// Kernel 2: final per-image reduction + k=256. One wave per image; plain stores.
// Lane l = block tile index within image (tr*8 + tc).
__global__ __launch_bounds__(64) void slice_k2(const float* __restrict__ ws,
                                               float* __restrict__ out) {
    const int b = blockIdx.x, l = threadIdx.x;
    const float4* g = (const float4*)(ws + ((size_t)b * 64 + l) * 8);
    float4 u0 = g[0], u1 = g[1];
    float v[8] = {u0.x, u0.y, u0.z, u0.w, u1.x, u1.y, u1.z, u1.w};

    // k=256 from per-block s128 (v[7]); x bit0 = lane bit0, y bit0 = lane bit3
    float s256 = v[7] + __shfl_xor(v[7], 1); s256 += __shfl_xor(s256, 8);
    float e256 = ent(s256, 1.f / 65536.f);
    float E256 = e256 + __shfl_xor(e256, 2); E256 += __shfl_xor(E256, 4);
    E256 += __shfl_xor(E256, 16);  E256 += __shfl_xor(E256, 32);  // 16 distinct

    float sums[7];
#pragma unroll
    for (int j = 0; j < 7; ++j) sums[j] = bfly_sum(v[j]);

    if (l == 0) {
        const float invw[7] = {1.f / 262144.f, 1.f / 65536.f, 1.f / 16384.f,
                               1.f / 4096.f,   1.f / 1024.f,  1.f / 256.f, 1.f / 64.f};
        float* o = out + b * 8;
#pragma unroll
        for (int j = 0; j < 7; ++j) o[j] = sums[j] * invw[j];
        o[7] = E256 * (1.f / 16.f);
    }
}

extern "C" void kernel_launch(void* const* d_in, const int* in_sizes, int n_in,
                              void* d_out, int out_size, void* d_ws, size_t ws_size,
                              hipStream_t stream) {
    const float* x = (const float*)d_in[0];
    float* out = (float*)d_out;
    float* ws  = (float*)d_ws;  // 2048 blocks * 8 floats = 64 KiB

    slice_k1<<<32 * 64, 256, 0, stream>>>(x, ws);
    slice_k2<<<32, 64, 0, stream>>>(ws, out);
}